// Round 1
// baseline (962.925 us; speedup 1.0000x reference)
//
#include <hip/hip_runtime.h>
#include <stdint.h>

#define B 8
#define N 1000
#define C 91
#define NC 90            // classes minus background
#define D 1024
#define KMAX 2048        // NMS_TOPK
#define PAD 4096         // sort capacity (V <= 4000 mathematically)
#define DETS 36
#define SCORE_THRESH 0.2f
#define NMS_THRESH 0.5f
#define MIN_SIZE 0.01f
#define XFORM_CLIP 4.135166556742356f   // log(1000/16)

// ---- shared decode so kernel1 and kernel3 produce identical boxes ----
__device__ __forceinline__ void decode_clip(const float* __restrict__ rg,
                                            float wdt, float hgt, float cx, float cy,
                                            float W, float H,
                                            float& x1, float& y1, float& x2, float& y2) {
    float dx = rg[0] / 10.0f;
    float dy = rg[1] / 10.0f;
    float dw = fminf(rg[2] / 5.0f, XFORM_CLIP);
    float dh = fminf(rg[3] / 5.0f, XFORM_CLIP);
    float pcx = dx * wdt + cx;
    float pcy = dy * hgt + cy;
    float pw  = expf(dw) * wdt;
    float ph  = expf(dh) * hgt;
    x1 = fminf(fmaxf(pcx - 0.5f * pw, 0.0f), W);
    y1 = fminf(fmaxf(pcy - 0.5f * ph, 0.0f), H);
    x2 = fminf(fmaxf(pcx + 0.5f * pw, 0.0f), W);
    y2 = fminf(fmaxf(pcy + 0.5f * ph, 0.0f), H);
}

// ---- kernel 1: softmax + decode + validity filter + compaction ----
// one thread per proposal row (B*N = 8000 threads)
__global__ void k_score(const float* __restrict__ logits,
                        const float* __restrict__ reg,
                        const float* __restrict__ props,
                        const int* __restrict__ img_hw,
                        int* __restrict__ counters,
                        unsigned long long* __restrict__ keys) {
    int r = blockIdx.x * blockDim.x + threadIdx.x;
    if (r >= B * N) return;
    int b = r / N, n = r % N;
    const float* lg = logits + (size_t)r * C;
    float m = lg[0];
    for (int c = 1; c < C; ++c) m = fmaxf(m, lg[c]);
    float s = 0.0f;
    for (int c = 0; c < C; ++c) s += expf(lg[c] - m);

    float p0 = props[r * 4 + 0], p1 = props[r * 4 + 1];
    float p2 = props[r * 4 + 2], p3 = props[r * 4 + 3];
    float wdt = p2 - p0, hgt = p3 - p1;
    float cx = p0 + 0.5f * wdt, cy = p1 + 0.5f * hgt;
    float H = (float)img_hw[b * 2 + 0];
    float W = (float)img_hw[b * 2 + 1];

    for (int c = 1; c < C; ++c) {
        float sc = expf(lg[c] - m) / s;
        if (sc > SCORE_THRESH) {
            const float* rg = reg + (size_t)r * (C * 4) + (size_t)c * 4;
            float x1, y1, x2, y2;
            decode_clip(rg, wdt, hgt, cx, cy, W, H, x1, y1, x2, y2);
            if ((x2 - x1) >= MIN_SIZE && (y2 - y1) >= MIN_SIZE) {
                int slot = atomicAdd(&counters[b], 1);
                if (slot < PAD) {
                    unsigned int idx = (unsigned int)(n * NC + (c - 1));
                    unsigned long long key =
                        ((unsigned long long)__float_as_uint(sc) << 32) |
                        (unsigned long long)(0xFFFFFFFFu - idx);
                    keys[(size_t)b * PAD + slot] = key;
                }
            }
        }
    }
}

// ---- kernel 2: per-image bitonic sort (descending) of up to 4096 keys ----
__global__ __launch_bounds__(512) void k_sort(const int* __restrict__ counters,
                                              int* __restrict__ Kvals,
                                              unsigned long long* __restrict__ keys) {
    __shared__ unsigned long long sk[PAD];
    int b = blockIdx.x;
    int V = counters[b];
    if (V > PAD) V = PAD;
    unsigned long long* kb = keys + (size_t)b * PAD;
    for (int t = threadIdx.x; t < PAD; t += blockDim.x)
        sk[t] = (t < V) ? kb[t] : 0ULL;
    __syncthreads();
    for (int k = 2; k <= PAD; k <<= 1) {
        for (int j = k >> 1; j > 0; j >>= 1) {
            for (int i = threadIdx.x; i < PAD; i += blockDim.x) {
                int l = i ^ j;
                if (l > i) {
                    unsigned long long a = sk[i], bb = sk[l];
                    bool up = ((i & k) == 0);   // descending overall
                    if (up ? (a < bb) : (a > bb)) { sk[i] = bb; sk[l] = a; }
                }
            }
            __syncthreads();
        }
    }
    for (int t = threadIdx.x; t < KMAX; t += blockDim.x) kb[t] = sk[t];
    if (threadIdx.x == 0) Kvals[b] = (V < KMAX) ? V : KMAX;
}

// ---- kernel 3: per-image sequential NMS + select first 36 kept ----
__global__ __launch_bounds__(256) void k_nms(const int* __restrict__ Kvals,
                                             const unsigned long long* __restrict__ keys,
                                             const float* __restrict__ reg,
                                             const float* __restrict__ props,
                                             const int* __restrict__ img_hw,
                                             int* __restrict__ sel) {
    __shared__ float sbox[KMAX][4];
    __shared__ int sidx[KMAX];
    __shared__ unsigned char skeep[KMAX];
    int b = blockIdx.x;
    int K = Kvals[b];
    const unsigned long long* kb = keys + (size_t)b * PAD;
    float H = (float)img_hw[b * 2 + 0];
    float W = (float)img_hw[b * 2 + 1];

    for (int t = threadIdx.x; t < KMAX; t += blockDim.x) {
        if (t < K) {
            unsigned long long key = kb[t];
            unsigned int idx = 0xFFFFFFFFu - (unsigned int)(key & 0xFFFFFFFFull);
            int n = (int)(idx / NC);
            int c = (int)(idx % NC) + 1;
            int r = b * N + n;
            float p0 = props[r * 4 + 0], p1 = props[r * 4 + 1];
            float p2 = props[r * 4 + 2], p3 = props[r * 4 + 3];
            float wdt = p2 - p0, hgt = p3 - p1;
            float cx = p0 + 0.5f * wdt, cy = p1 + 0.5f * hgt;
            const float* rg = reg + (size_t)r * (C * 4) + (size_t)c * 4;
            float x1, y1, x2, y2;
            decode_clip(rg, wdt, hgt, cx, cy, W, H, x1, y1, x2, y2);
            sbox[t][0] = x1; sbox[t][1] = y1; sbox[t][2] = x2; sbox[t][3] = y2;
            sidx[t] = (int)idx;
            skeep[t] = 1;
        } else {
            skeep[t] = 0;
        }
    }
    __syncthreads();

    for (int i = 0; i < K; ++i) {
        if (skeep[i]) {
            float ax1 = sbox[i][0], ay1 = sbox[i][1];
            float ax2 = sbox[i][2], ay2 = sbox[i][3];
            float aarea = (ax2 - ax1) * (ay2 - ay1);
            for (int j = i + 1 + threadIdx.x; j < K; j += blockDim.x) {
                if (skeep[j]) {
                    float b1 = sbox[j][0], b2 = sbox[j][1];
                    float b3 = sbox[j][2], b4 = sbox[j][3];
                    float barea = (b3 - b1) * (b4 - b2);
                    float ix1 = fmaxf(ax1, b1), iy1 = fmaxf(ay1, b2);
                    float ix2 = fminf(ax2, b3), iy2 = fminf(ay2, b4);
                    float iw = fmaxf(ix2 - ix1, 0.0f);
                    float ih = fmaxf(iy2 - iy1, 0.0f);
                    float inter = iw * ih;
                    float uni = aarea + barea - inter;
                    float iou = (uni > 0.0f) ? (inter / uni) : 0.0f;
                    if (iou > NMS_THRESH) skeep[j] = 0;
                }
            }
        }
        __syncthreads();
    }

    if (threadIdx.x == 0) {
        int cnt = 0;
        for (int i = 0; i < K && cnt < DETS; ++i)
            if (skeep[i]) { sel[b * DETS + cnt] = sidx[i] / NC; ++cnt; }
        for (; cnt < DETS; ++cnt) sel[b * DETS + cnt] = -1;
    }
}

// ---- kernel 4: gather feature rows (or zeros) into output ----
__global__ __launch_bounds__(256) void k_gather(const int* __restrict__ sel,
                                                const float* __restrict__ feats,
                                                float* __restrict__ out) {
    int slot = blockIdx.x;            // b*DETS + s
    int b = slot / DETS;
    int row = sel[slot];
    float4* o = (float4*)(out + (size_t)slot * D);
    if (row >= 0) {
        const float4* f = (const float4*)(feats + ((size_t)b * N + row) * D);
        o[threadIdx.x] = f[threadIdx.x];
    } else {
        o[threadIdx.x] = make_float4(0.f, 0.f, 0.f, 0.f);
    }
}

extern "C" void kernel_launch(void* const* d_in, const int* in_sizes, int n_in,
                              void* d_out, int out_size, void* d_ws, size_t ws_size,
                              hipStream_t stream) {
    const float* logits = (const float*)d_in[0];   // [B,N,C]
    const float* reg    = (const float*)d_in[1];   // [B,N,C*4]
    const float* props  = (const float*)d_in[2];   // [B,N,4]
    const float* feats  = (const float*)d_in[3];   // [B,N,D]
    const int*   img    = (const int*)d_in[4];     // [B,2]
    float* out = (float*)d_out;                    // [B,DETS,D]

    char* ws = (char*)d_ws;
    int* counters = (int*)ws;                              // 8 ints
    int* Kvals    = (int*)(ws + 64);                       // 8 ints
    int* sel      = (int*)(ws + 128);                      // 8*36 ints
    unsigned long long* keys = (unsigned long long*)(ws + 4096);  // 8*4096 u64

    hipMemsetAsync(counters, 0, 64, stream);
    k_score<<<dim3((B * N + 255) / 256), dim3(256), 0, stream>>>(
        logits, reg, props, img, counters, keys);
    k_sort<<<dim3(B), dim3(512), 0, stream>>>(counters, Kvals, keys);
    k_nms<<<dim3(B), dim3(256), 0, stream>>>(Kvals, keys, reg, props, img, sel);
    k_gather<<<dim3(B * DETS), dim3(256), 0, stream>>>(sel, feats, out);
}

// Round 2
// 296.965 us; speedup vs baseline: 3.2426x; 3.2426x over previous
//
#include <hip/hip_runtime.h>
#include <stdint.h>

#define B 8
#define N 1000
#define C 91
#define NC 90            // classes minus background
#define D 1024
#define KMAX 2048        // NMS_TOPK
#define PAD 4096         // sort capacity (V <= 4000 mathematically: softmax sums to 1 -> <=4 classes/row exceed 0.2)
#define DETS 36
#define SCORE_THRESH 0.2f
#define NMS_THRESH 0.5f
#define MIN_SIZE 0.01f
#define XFORM_CLIP 4.135166556742356f   // log(1000/16)

// ---- shared decode so all kernels produce bit-identical boxes ----
__device__ __forceinline__ void decode_clip(const float* __restrict__ rg,
                                            float wdt, float hgt, float cx, float cy,
                                            float W, float H,
                                            float& x1, float& y1, float& x2, float& y2) {
    float dx = rg[0] / 10.0f;
    float dy = rg[1] / 10.0f;
    float dw = fminf(rg[2] / 5.0f, XFORM_CLIP);
    float dh = fminf(rg[3] / 5.0f, XFORM_CLIP);
    float pcx = dx * wdt + cx;
    float pcy = dy * hgt + cy;
    float pw  = expf(dw) * wdt;
    float ph  = expf(dh) * hgt;
    x1 = fminf(fmaxf(pcx - 0.5f * pw, 0.0f), W);
    y1 = fminf(fmaxf(pcy - 0.5f * ph, 0.0f), H);
    x2 = fminf(fmaxf(pcx + 0.5f * pw, 0.0f), W);
    y2 = fminf(fmaxf(pcy + 0.5f * ph, 0.0f), H);
}

// ---- kernel 1: one WAVE per proposal row. Serial softmax kept in the exact
// order of the round-1 passing kernel (redundant per-lane) to avoid ulp flips
// at the 0.2 boundary; lanes then fan out over classes for decode+filter.
__global__ __launch_bounds__(256) void k_score(const float* __restrict__ logits,
                        const float* __restrict__ reg,
                        const float* __restrict__ props,
                        const int* __restrict__ img_hw,
                        int* __restrict__ counters,
                        unsigned long long* __restrict__ keys) {
    int gid = blockIdx.x * 256 + threadIdx.x;
    int r = gid >> 6;                    // one row per wave
    if (r >= B * N) return;
    int lane = threadIdx.x & 63;
    int wib  = threadIdx.x >> 6;
    int b = r / N, n = r % N;

    __shared__ float slg[4][C];
    const float* lg = logits + (size_t)r * C;
    slg[wib][lane] = lg[lane];                       // coalesced row load
    if (lane < C - 64) slg[wib][lane + 64] = lg[lane + 64];
    // same-wave LDS RAW: compiler inserts lgkmcnt; no barrier needed (per-wave slot)

    float m = slg[wib][0];
    for (int c = 1; c < C; ++c) m = fmaxf(m, slg[wib][c]);
    float s = 0.0f;
    for (int c = 0; c < C; ++c) s += expf(slg[wib][c] - m);   // serial order == R1

    float p0 = props[r * 4 + 0], p1 = props[r * 4 + 1];
    float p2 = props[r * 4 + 2], p3 = props[r * 4 + 3];
    float wdt = p2 - p0, hgt = p3 - p1;
    float cx = p0 + 0.5f * wdt, cy = p1 + 0.5f * hgt;
    float H = (float)img_hw[b * 2 + 0];
    float W = (float)img_hw[b * 2 + 1];

    #pragma unroll
    for (int t2 = 0; t2 < 2; ++t2) {
        int c = 1 + lane + t2 * 64;
        if (c < C) {
            float sc = expf(slg[wib][c] - m) / s;
            if (sc > SCORE_THRESH) {
                const float* rg = reg + (size_t)r * (C * 4) + (size_t)c * 4;
                float x1, y1, x2, y2;
                decode_clip(rg, wdt, hgt, cx, cy, W, H, x1, y1, x2, y2);
                if ((x2 - x1) >= MIN_SIZE && (y2 - y1) >= MIN_SIZE) {
                    int slot = atomicAdd(&counters[b], 1);
                    if (slot < PAD) {
                        unsigned int idx = (unsigned int)(n * NC + (c - 1));
                        unsigned long long key =
                            ((unsigned long long)__float_as_uint(sc) << 32) |
                            (unsigned long long)(0xFFFFFFFFu - idx);
                        keys[(size_t)b * PAD + slot] = key;
                    }
                }
            }
        }
    }
}

// ---- kernel 2: per-image bitonic sort (descending) + decode top-K boxes ----
__global__ __launch_bounds__(1024) void k_sort(const int* __restrict__ counters,
                                               int* __restrict__ Kvals,
                                               unsigned long long* __restrict__ keys,
                                               const float* __restrict__ reg,
                                               const float* __restrict__ props,
                                               const int* __restrict__ img_hw,
                                               float* __restrict__ bx1, float* __restrict__ by1,
                                               float* __restrict__ bx2, float* __restrict__ by2,
                                               int* __restrict__ propn) {
    __shared__ unsigned long long sk[PAD];
    int b = blockIdx.x;
    int V = counters[b];
    if (V > PAD) V = PAD;
    unsigned long long* kb = keys + (size_t)b * PAD;
    for (int t = threadIdx.x; t < PAD; t += 1024)
        sk[t] = (t < V) ? kb[t] : 0ULL;
    __syncthreads();
    for (int k = 2; k <= PAD; k <<= 1) {
        for (int j = k >> 1; j > 0; j >>= 1) {
            for (int i = threadIdx.x; i < PAD; i += 1024) {
                int l = i ^ j;
                if (l > i) {
                    unsigned long long a = sk[i], bb = sk[l];
                    bool up = ((i & k) == 0);   // descending overall
                    if (up ? (a < bb) : (a > bb)) { sk[i] = bb; sk[l] = a; }
                }
            }
            __syncthreads();
        }
    }
    int K = (V < KMAX) ? V : KMAX;
    float H = (float)img_hw[b * 2 + 0];
    float W = (float)img_hw[b * 2 + 1];
    for (int t = threadIdx.x; t < KMAX; t += 1024) {
        size_t o = (size_t)b * KMAX + t;
        if (t < K) {
            unsigned long long key = sk[t];
            unsigned int idx = 0xFFFFFFFFu - (unsigned int)(key & 0xFFFFFFFFull);
            int n = (int)(idx / NC);
            int c = (int)(idx % NC) + 1;
            int r = b * N + n;
            float p0 = props[r * 4 + 0], p1 = props[r * 4 + 1];
            float p2 = props[r * 4 + 2], p3 = props[r * 4 + 3];
            float wdt = p2 - p0, hgt = p3 - p1;
            float cx = p0 + 0.5f * wdt, cy = p1 + 0.5f * hgt;
            const float* rg = reg + (size_t)r * (C * 4) + (size_t)c * 4;
            float x1, y1, x2, y2;
            decode_clip(rg, wdt, hgt, cx, cy, W, H, x1, y1, x2, y2);
            bx1[o] = x1; by1[o] = y1; bx2[o] = x2; by2[o] = y2;
            propn[o] = n;
        } else {
            bx1[o] = 0.f; by1[o] = 0.f; bx2[o] = 0.f; by2[o] = 0.f;
            propn[o] = 0;
        }
    }
    if (threadIdx.x == 0) Kvals[b] = K;
}

// ---- kernel 3: parallel suppression-mask matrix. thread -> one u64 word:
// row i, columns w*64..w*64+63. Boxes staged SoA in LDS; column reads skewed
// by w so the 32 word-lanes hit 32 distinct banks (unskewed = 32-way conflict).
__global__ __launch_bounds__(256) void k_mask(const int* __restrict__ Kvals,
                                              const float* __restrict__ bx1, const float* __restrict__ by1,
                                              const float* __restrict__ bx2, const float* __restrict__ by2,
                                              unsigned long long* __restrict__ mask) {
    int b = blockIdx.y;
    int K = Kvals[b];
    int base_word = blockIdx.x * 256;
    int row0 = base_word >> 5;
    if (row0 >= K) return;

    __shared__ float sx1[KMAX], sy1[KMAX], sx2[KMAX], sy2[KMAX];
    const float* px1 = bx1 + (size_t)b * KMAX;
    const float* py1 = by1 + (size_t)b * KMAX;
    const float* px2 = bx2 + (size_t)b * KMAX;
    const float* py2 = by2 + (size_t)b * KMAX;
    for (int t = threadIdx.x; t < KMAX; t += 256) {
        sx1[t] = px1[t]; sy1[t] = py1[t]; sx2[t] = px2[t]; sy2[t] = py2[t];
    }
    __syncthreads();

    int word = base_word + threadIdx.x;
    int i = word >> 5, w = word & 31;
    unsigned long long acc = 0ULL;
    if (i < K) {
        float ax1 = sx1[i], ay1 = sy1[i], ax2 = sx2[i], ay2 = sy2[i];
        float aarea = (ax2 - ax1) * (ay2 - ay1);
        for (int bb = 0; bb < 64; ++bb) {
            int off = (bb + w) & 63;          // bank-conflict skew
            int j = (w << 6) + off;
            float q1 = sx1[j], q2 = sy1[j], q3 = sx2[j], q4 = sy2[j];
            float barea = (q3 - q1) * (q4 - q2);
            float ix1 = fmaxf(ax1, q1), iy1 = fmaxf(ay1, q2);
            float ix2 = fminf(ax2, q3), iy2 = fminf(ay2, q4);
            float iw = fmaxf(ix2 - ix1, 0.0f);
            float ih = fmaxf(iy2 - iy1, 0.0f);
            float inter = iw * ih;
            float uni = aarea + barea - inter;
            float iou = (uni > 0.0f) ? (inter / uni) : 0.0f;
            if (j > i && j < K && iou > NMS_THRESH) acc |= (1ULL << off);
        }
        mask[((size_t)b * KMAX + i) * 32 + w] = acc;
    }
}

// ---- kernel 4: bit-parallel sequential scan. one wave per image; lane l<32
// holds removed-word l in a register. Per candidate: one shfl (uniform branch)
// + conditional OR of the prefetched (double-buffered) mask row. Early exit
// once DETS kept (later decisions cannot affect the first 36).
#define CH 16
__global__ __launch_bounds__(64) void k_scan(const int* __restrict__ Kvals,
                                             const unsigned long long* __restrict__ mask,
                                             const int* __restrict__ propn,
                                             int* __restrict__ sel) {
    int b = blockIdx.x, lane = threadIdx.x;
    int K = Kvals[b];
    const unsigned long long* mb = mask + (size_t)b * KMAX * 32;
    const int* pb = propn + (size_t)b * KMAX;
    unsigned long long removed = 0ULL;
    unsigned long long cur[CH], nxt[CH];
    int pcur = 0, pnxt = 0;
    int cnt = 0;
    bool done = (K <= 0);

    if (!done) {
        #pragma unroll
        for (int q = 0; q < CH; ++q)
            cur[q] = (lane < 32) ? mb[(size_t)q * 32 + lane] : 0ULL;
        pcur = (lane < CH) ? pb[lane] : 0;
    }

    for (int base = 0; base < K; base += CH) {
        if (done) break;
        int nb = base + CH;
        #pragma unroll
        for (int q = 0; q < CH; ++q) {
            int row = nb + q; if (row > KMAX - 1) row = KMAX - 1;
            nxt[q] = (lane < 32) ? mb[(size_t)row * 32 + lane] : 0ULL;
        }
        {
            int row = nb + lane; if (row > KMAX - 1) row = KMAX - 1;
            pnxt = (lane < CH) ? pb[row] : 0;
        }
        #pragma unroll
        for (int q = 0; q < CH; ++q) {
            int i = base + q;
            if (!done && i < K) {
                int owner = i >> 6;
                unsigned long long wword = __shfl(removed, owner, 64); // uniform
                if (!((wword >> (i & 63)) & 1ULL)) {
                    int pv = __shfl(pcur, q, 64);
                    removed |= cur[q];
                    if (lane == 0) sel[b * DETS + cnt] = pv;
                    ++cnt;
                    if (cnt == DETS) done = true;
                }
            }
        }
        #pragma unroll
        for (int q = 0; q < CH; ++q) cur[q] = nxt[q];
        pcur = pnxt;
    }
    if (lane == 0)
        for (int q = cnt; q < DETS; ++q) sel[b * DETS + q] = -1;
}

// ---- kernel 5: gather feature rows (or zeros) into output ----
__global__ __launch_bounds__(256) void k_gather(const int* __restrict__ sel,
                                                const float* __restrict__ feats,
                                                float* __restrict__ out) {
    int slot = blockIdx.x;            // b*DETS + s
    int b = slot / DETS;
    int row = sel[slot];
    float4* o = (float4*)(out + (size_t)slot * D);
    if (row >= 0) {
        const float4* f = (const float4*)(feats + ((size_t)b * N + row) * D);
        o[threadIdx.x] = f[threadIdx.x];
    } else {
        o[threadIdx.x] = make_float4(0.f, 0.f, 0.f, 0.f);
    }
}

extern "C" void kernel_launch(void* const* d_in, const int* in_sizes, int n_in,
                              void* d_out, int out_size, void* d_ws, size_t ws_size,
                              hipStream_t stream) {
    const float* logits = (const float*)d_in[0];   // [B,N,C]
    const float* reg    = (const float*)d_in[1];   // [B,N,C*4]
    const float* props  = (const float*)d_in[2];   // [B,N,4]
    const float* feats  = (const float*)d_in[3];   // [B,N,D]
    const int*   img    = (const int*)d_in[4];     // [B,2]
    float* out = (float*)d_out;                    // [B,DETS,D]

    char* ws = (char*)d_ws;
    int* counters = (int*)(ws + 0);                        // 8 ints
    int* Kvals    = (int*)(ws + 256);                      // 8 ints
    int* sel      = (int*)(ws + 512);                      // 8*36 ints
    unsigned long long* keys = (unsigned long long*)(ws + 4096);      // 8*4096 u64 = 256KB
    float* bx1 = (float*)(ws + 270336);                    // each 8*2048*4 = 64KB
    float* by1 = (float*)(ws + 335872);
    float* bx2 = (float*)(ws + 401408);
    float* by2 = (float*)(ws + 466944);
    int*   propn = (int*)(ws + 532480);                    // 64KB
    unsigned long long* mask = (unsigned long long*)(ws + 598016);    // 8*2048*32 u64 = 4MB

    hipMemsetAsync(counters, 0, 64, stream);
    k_score<<<dim3((B * N * 64) / 256), dim3(256), 0, stream>>>(
        logits, reg, props, img, counters, keys);
    k_sort<<<dim3(B), dim3(1024), 0, stream>>>(counters, Kvals, keys,
        reg, props, img, bx1, by1, bx2, by2, propn);
    k_mask<<<dim3(256, B), dim3(256), 0, stream>>>(Kvals, bx1, by1, bx2, by2, mask);
    k_scan<<<dim3(B), dim3(64), 0, stream>>>(Kvals, mask, propn, sel);
    k_gather<<<dim3(B * DETS), dim3(256), 0, stream>>>(sel, feats, out);
}

// Round 3
// 190.513 us; speedup vs baseline: 5.0544x; 1.5588x over previous
//
#include <hip/hip_runtime.h>
#include <stdint.h>

#define B 8
#define N 1000
#define C 91
#define NC 90            // classes minus background
#define D 1024
#define KMAX 2048        // NMS_TOPK
#define PAD 4096         // sort capacity (V <= 4000: softmax sums to 1 -> <=4 classes/row exceed 0.2)
#define DETS 36
#define SCORE_THRESH 0.2f
#define NMS_THRESH 0.5f
#define MIN_SIZE 0.01f
#define XFORM_CLIP 4.135166556742356f   // log(1000/16)
#define CSTRIDE 64       // counter padding: 64 ints = 256 B per image -> separate L2 lines

// ---- shared decode so all kernels produce bit-identical boxes ----
__device__ __forceinline__ void decode_clip(const float* __restrict__ rg,
                                            float wdt, float hgt, float cx, float cy,
                                            float W, float H,
                                            float& x1, float& y1, float& x2, float& y2) {
    float dx = rg[0] / 10.0f;
    float dy = rg[1] / 10.0f;
    float dw = fminf(rg[2] / 5.0f, XFORM_CLIP);
    float dh = fminf(rg[3] / 5.0f, XFORM_CLIP);
    float pcx = dx * wdt + cx;
    float pcy = dy * hgt + cy;
    float pw  = expf(dw) * wdt;
    float ph  = expf(dh) * hgt;
    x1 = fminf(fmaxf(pcx - 0.5f * pw, 0.0f), W);
    y1 = fminf(fmaxf(pcy - 0.5f * ph, 0.0f), H);
    x2 = fminf(fmaxf(pcx + 0.5f * pw, 0.0f), W);
    y2 = fminf(fmaxf(pcy + 0.5f * ph, 0.0f), H);
}

// ---- kernel 1: one wave per row, CLASS-PARALLEL softmax.
// lane l holds classes l and l+64. Wave butterfly max (fmax: order-exact),
// butterfly sum (ulp-level reorder vs serial -- decisions have margin).
// Candidates compacted in LDS; ONE global atomic per block on a padded counter.
__global__ __launch_bounds__(256) void k_score(const float* __restrict__ logits,
                        const float* __restrict__ reg,
                        const float* __restrict__ props,
                        const int* __restrict__ img_hw,
                        int* __restrict__ counters,
                        unsigned long long* __restrict__ keys) {
    int b = blockIdx.x / 250;            // 250 blocks per image, 4 rows per block
    int local = blockIdx.x % 250;
    int wib = threadIdx.x >> 6, lane = threadIdx.x & 63;
    int n = local * 4 + wib;
    int r = b * N + n;

    __shared__ unsigned long long cand[32];   // <=16 possible (4 rows x <=4 classes)
    __shared__ int lcnt;
    __shared__ int gbase;
    if (threadIdx.x == 0) lcnt = 0;
    __syncthreads();

    const float* lg = logits + (size_t)r * C;
    float v0 = lg[lane];                                  // classes 0..63
    float v1 = (lane < C - 64) ? lg[64 + lane] : -3.4e38f; // classes 64..90
    float m = fmaxf(v0, v1);
    #pragma unroll
    for (int off = 32; off; off >>= 1) m = fmaxf(m, __shfl_xor(m, off, 64));
    float e0 = expf(v0 - m);
    float e1 = (lane < C - 64) ? expf(v1 - m) : 0.0f;
    float s = e0 + e1;
    #pragma unroll
    for (int off = 32; off; off >>= 1) s += __shfl_xor(s, off, 64);

    float p0 = props[r * 4 + 0], p1 = props[r * 4 + 1];
    float p2 = props[r * 4 + 2], p3 = props[r * 4 + 3];
    float wdt = p2 - p0, hgt = p3 - p1;
    float cx = p0 + 0.5f * wdt, cy = p1 + 0.5f * hgt;
    float H = (float)img_hw[b * 2 + 0];
    float W = (float)img_hw[b * 2 + 1];

    #pragma unroll
    for (int t2 = 0; t2 < 2; ++t2) {
        int c = lane + t2 * 64;
        float e = t2 ? e1 : e0;
        if (c >= 1 && c < C) {
            float sc = e / s;
            if (sc > SCORE_THRESH) {
                const float* rg = reg + (size_t)r * (C * 4) + (size_t)c * 4;
                float x1, y1, x2, y2;
                decode_clip(rg, wdt, hgt, cx, cy, W, H, x1, y1, x2, y2);
                if ((x2 - x1) >= MIN_SIZE && (y2 - y1) >= MIN_SIZE) {
                    unsigned int idx = (unsigned int)(n * NC + (c - 1));
                    unsigned long long key =
                        ((unsigned long long)__float_as_uint(sc) << 32) |
                        (unsigned long long)(0xFFFFFFFFu - idx);
                    int p = atomicAdd(&lcnt, 1);          // LDS atomic: cheap
                    cand[p] = key;
                }
            }
        }
    }
    __syncthreads();
    if (threadIdx.x == 0 && lcnt > 0)
        gbase = atomicAdd(&counters[b * CSTRIDE], lcnt);  // one global atomic/block
    __syncthreads();
    if (threadIdx.x < lcnt)
        keys[(size_t)b * PAD + gbase + threadIdx.x] = cand[threadIdx.x];
}

// ---- kernel 2: per-image bitonic sort (descending) + decode top-K boxes ----
__global__ __launch_bounds__(1024) void k_sort(const int* __restrict__ counters,
                                               int* __restrict__ Kvals,
                                               unsigned long long* __restrict__ keys,
                                               const float* __restrict__ reg,
                                               const float* __restrict__ props,
                                               const int* __restrict__ img_hw,
                                               float* __restrict__ bx1, float* __restrict__ by1,
                                               float* __restrict__ bx2, float* __restrict__ by2,
                                               int* __restrict__ propn) {
    __shared__ unsigned long long sk[PAD];
    int b = blockIdx.x;
    int V = counters[b * CSTRIDE];
    if (V > PAD) V = PAD;
    unsigned long long* kb = keys + (size_t)b * PAD;
    for (int t = threadIdx.x; t < PAD; t += 1024)
        sk[t] = (t < V) ? kb[t] : 0ULL;
    __syncthreads();
    for (int k = 2; k <= PAD; k <<= 1) {
        for (int j = k >> 1; j > 0; j >>= 1) {
            for (int i = threadIdx.x; i < PAD; i += 1024) {
                int l = i ^ j;
                if (l > i) {
                    unsigned long long a = sk[i], bb = sk[l];
                    bool up = ((i & k) == 0);   // descending overall
                    if (up ? (a < bb) : (a > bb)) { sk[i] = bb; sk[l] = a; }
                }
            }
            __syncthreads();
        }
    }
    int K = (V < KMAX) ? V : KMAX;
    float H = (float)img_hw[b * 2 + 0];
    float W = (float)img_hw[b * 2 + 1];
    for (int t = threadIdx.x; t < KMAX; t += 1024) {
        size_t o = (size_t)b * KMAX + t;
        if (t < K) {
            unsigned long long key = sk[t];
            unsigned int idx = 0xFFFFFFFFu - (unsigned int)(key & 0xFFFFFFFFull);
            int n = (int)(idx / NC);
            int c = (int)(idx % NC) + 1;
            int r = b * N + n;
            float p0 = props[r * 4 + 0], p1 = props[r * 4 + 1];
            float p2 = props[r * 4 + 2], p3 = props[r * 4 + 3];
            float wdt = p2 - p0, hgt = p3 - p1;
            float cx = p0 + 0.5f * wdt, cy = p1 + 0.5f * hgt;
            const float* rg = reg + (size_t)r * (C * 4) + (size_t)c * 4;
            float x1, y1, x2, y2;
            decode_clip(rg, wdt, hgt, cx, cy, W, H, x1, y1, x2, y2);
            bx1[o] = x1; by1[o] = y1; bx2[o] = x2; by2[o] = y2;
            propn[o] = n;
        } else {
            bx1[o] = 0.f; by1[o] = 0.f; bx2[o] = 0.f; by2[o] = 0.f;
            propn[o] = 0;
        }
    }
    if (threadIdx.x == 0) Kvals[b] = K;
}

// ---- kernel 3: parallel suppression-mask matrix. thread -> one u64 word:
// row i, columns w*64..w*64+63. Boxes staged SoA in LDS; column reads skewed
// by w so the 32 word-lanes hit 32 distinct banks (unskewed = 32-way conflict).
__global__ __launch_bounds__(256) void k_mask(const int* __restrict__ Kvals,
                                              const float* __restrict__ bx1, const float* __restrict__ by1,
                                              const float* __restrict__ bx2, const float* __restrict__ by2,
                                              unsigned long long* __restrict__ mask) {
    int b = blockIdx.y;
    int K = Kvals[b];
    int base_word = blockIdx.x * 256;
    int row0 = base_word >> 5;
    if (row0 >= K) return;

    __shared__ float sx1[KMAX], sy1[KMAX], sx2[KMAX], sy2[KMAX];
    const float* px1 = bx1 + (size_t)b * KMAX;
    const float* py1 = by1 + (size_t)b * KMAX;
    const float* px2 = bx2 + (size_t)b * KMAX;
    const float* py2 = by2 + (size_t)b * KMAX;
    for (int t = threadIdx.x; t < KMAX; t += 256) {
        sx1[t] = px1[t]; sy1[t] = py1[t]; sx2[t] = px2[t]; sy2[t] = py2[t];
    }
    __syncthreads();

    int word = base_word + threadIdx.x;
    int i = word >> 5, w = word & 31;
    unsigned long long acc = 0ULL;
    if (i < K) {
        float ax1 = sx1[i], ay1 = sy1[i], ax2 = sx2[i], ay2 = sy2[i];
        float aarea = (ax2 - ax1) * (ay2 - ay1);
        for (int bb = 0; bb < 64; ++bb) {
            int off = (bb + w) & 63;          // bank-conflict skew
            int j = (w << 6) + off;
            float q1 = sx1[j], q2 = sy1[j], q3 = sx2[j], q4 = sy2[j];
            float barea = (q3 - q1) * (q4 - q2);
            float ix1 = fmaxf(ax1, q1), iy1 = fmaxf(ay1, q2);
            float ix2 = fminf(ax2, q3), iy2 = fminf(ay2, q4);
            float iw = fmaxf(ix2 - ix1, 0.0f);
            float ih = fmaxf(iy2 - iy1, 0.0f);
            float inter = iw * ih;
            float uni = aarea + barea - inter;
            float iou = (uni > 0.0f) ? (inter / uni) : 0.0f;
            if (j > i && j < K && iou > NMS_THRESH) acc |= (1ULL << off);
        }
        mask[((size_t)b * KMAX + i) * 32 + w] = acc;
    }
}

// ---- kernel 4: bit-parallel sequential scan. one wave per image; lane l<32
// holds removed-word l in a register. Per candidate: one shfl (uniform branch)
// + conditional OR of the prefetched (double-buffered) mask row. Early exit
// once DETS kept (later decisions cannot affect the first 36).
#define CH 16
__global__ __launch_bounds__(64) void k_scan(const int* __restrict__ Kvals,
                                             const unsigned long long* __restrict__ mask,
                                             const int* __restrict__ propn,
                                             int* __restrict__ sel) {
    int b = blockIdx.x, lane = threadIdx.x;
    int K = Kvals[b];
    const unsigned long long* mb = mask + (size_t)b * KMAX * 32;
    const int* pb = propn + (size_t)b * KMAX;
    unsigned long long removed = 0ULL;
    unsigned long long cur[CH], nxt[CH];
    int pcur = 0, pnxt = 0;
    int cnt = 0;
    bool done = (K <= 0);

    if (!done) {
        #pragma unroll
        for (int q = 0; q < CH; ++q)
            cur[q] = (lane < 32) ? mb[(size_t)q * 32 + lane] : 0ULL;
        pcur = (lane < CH) ? pb[lane] : 0;
    }

    for (int base = 0; base < K; base += CH) {
        if (done) break;
        int nb = base + CH;
        #pragma unroll
        for (int q = 0; q < CH; ++q) {
            int row = nb + q; if (row > KMAX - 1) row = KMAX - 1;
            nxt[q] = (lane < 32) ? mb[(size_t)row * 32 + lane] : 0ULL;
        }
        {
            int row = nb + lane; if (row > KMAX - 1) row = KMAX - 1;
            pnxt = (lane < CH) ? pb[row] : 0;
        }
        #pragma unroll
        for (int q = 0; q < CH; ++q) {
            int i = base + q;
            if (!done && i < K) {
                int owner = i >> 6;
                unsigned long long wword = __shfl(removed, owner, 64); // uniform
                if (!((wword >> (i & 63)) & 1ULL)) {
                    int pv = __shfl(pcur, q, 64);
                    removed |= cur[q];
                    if (lane == 0) sel[b * DETS + cnt] = pv;
                    ++cnt;
                    if (cnt == DETS) done = true;
                }
            }
        }
        #pragma unroll
        for (int q = 0; q < CH; ++q) cur[q] = nxt[q];
        pcur = pnxt;
    }
    if (lane == 0)
        for (int q = cnt; q < DETS; ++q) sel[b * DETS + q] = -1;
}

// ---- kernel 5: gather feature rows (or zeros) into output ----
__global__ __launch_bounds__(256) void k_gather(const int* __restrict__ sel,
                                                const float* __restrict__ feats,
                                                float* __restrict__ out) {
    int slot = blockIdx.x;            // b*DETS + s
    int b = slot / DETS;
    int row = sel[slot];
    float4* o = (float4*)(out + (size_t)slot * D);
    if (row >= 0) {
        const float4* f = (const float4*)(feats + ((size_t)b * N + row) * D);
        o[threadIdx.x] = f[threadIdx.x];
    } else {
        o[threadIdx.x] = make_float4(0.f, 0.f, 0.f, 0.f);
    }
}

extern "C" void kernel_launch(void* const* d_in, const int* in_sizes, int n_in,
                              void* d_out, int out_size, void* d_ws, size_t ws_size,
                              hipStream_t stream) {
    const float* logits = (const float*)d_in[0];   // [B,N,C]
    const float* reg    = (const float*)d_in[1];   // [B,N,C*4]
    const float* props  = (const float*)d_in[2];   // [B,N,4]
    const float* feats  = (const float*)d_in[3];   // [B,N,D]
    const int*   img    = (const int*)d_in[4];     // [B,2]
    float* out = (float*)d_out;                    // [B,DETS,D]

    char* ws = (char*)d_ws;
    int* counters = (int*)(ws + 0);                        // 8 ints padded to 256 B each
    int* Kvals    = (int*)(ws + 2048);                     // 8 ints
    int* sel      = (int*)(ws + 2304);                     // 8*36 ints
    unsigned long long* keys = (unsigned long long*)(ws + 4096);      // 8*4096 u64 = 256KB
    float* bx1 = (float*)(ws + 270336);                    // each 8*2048*4 = 64KB
    float* by1 = (float*)(ws + 335872);
    float* bx2 = (float*)(ws + 401408);
    float* by2 = (float*)(ws + 466944);
    int*   propn = (int*)(ws + 532480);                    // 64KB
    unsigned long long* mask = (unsigned long long*)(ws + 598016);    // 8*2048*32 u64 = 4MB

    hipMemsetAsync(counters, 0, 2048, stream);
    k_score<<<dim3(B * 250), dim3(256), 0, stream>>>(
        logits, reg, props, img, counters, keys);
    k_sort<<<dim3(B), dim3(1024), 0, stream>>>(counters, Kvals, keys,
        reg, props, img, bx1, by1, bx2, by2, propn);
    k_mask<<<dim3(256, B), dim3(256), 0, stream>>>(Kvals, bx1, by1, bx2, by2, mask);
    k_scan<<<dim3(B), dim3(64), 0, stream>>>(Kvals, mask, propn, sel);
    k_gather<<<dim3(B * DETS), dim3(256), 0, stream>>>(sel, feats, out);
}

// Round 4
// 163.483 us; speedup vs baseline: 5.8901x; 1.1653x over previous
//
#include <hip/hip_runtime.h>
#include <stdint.h>

#define B 8
#define N 1000
#define C 91
#define NC 90            // classes minus background
#define D 1024
#define KMAX 2048        // NMS_TOPK
#define PAD 4096         // candidate capacity (V <= 4000: softmax sums to 1 -> <=4 classes/row exceed 0.2)
#define DETS 36
#define SCORE_THRESH 0.2f
#define NMS_THRESH 0.5f
#define MIN_SIZE 0.01f
#define XFORM_CLIP 4.135166556742356f   // log(1000/16)
#define CSTRIDE 64       // counter padding: 64 ints = 256 B per image -> separate L2 lines

// ---- shared decode so all kernels produce bit-identical boxes ----
__device__ __forceinline__ void decode_clip(const float* __restrict__ rg,
                                            float wdt, float hgt, float cx, float cy,
                                            float W, float H,
                                            float& x1, float& y1, float& x2, float& y2) {
    float dx = rg[0] / 10.0f;
    float dy = rg[1] / 10.0f;
    float dw = fminf(rg[2] / 5.0f, XFORM_CLIP);
    float dh = fminf(rg[3] / 5.0f, XFORM_CLIP);
    float pcx = dx * wdt + cx;
    float pcy = dy * hgt + cy;
    float pw  = expf(dw) * wdt;
    float ph  = expf(dh) * hgt;
    x1 = fminf(fmaxf(pcx - 0.5f * pw, 0.0f), W);
    y1 = fminf(fmaxf(pcy - 0.5f * ph, 0.0f), H);
    x2 = fminf(fmaxf(pcx + 0.5f * pw, 0.0f), W);
    y2 = fminf(fmaxf(pcy + 0.5f * ph, 0.0f), H);
}

// ---- kernel 1: one wave per row, class-parallel softmax (unchanged from R3) ----
__global__ __launch_bounds__(256) void k_score(const float* __restrict__ logits,
                        const float* __restrict__ reg,
                        const float* __restrict__ props,
                        const int* __restrict__ img_hw,
                        int* __restrict__ counters,
                        unsigned long long* __restrict__ keys) {
    int b = blockIdx.x / 250;            // 250 blocks per image, 4 rows per block
    int local = blockIdx.x % 250;
    int wib = threadIdx.x >> 6, lane = threadIdx.x & 63;
    int n = local * 4 + wib;
    int r = b * N + n;

    __shared__ unsigned long long cand[32];   // <=16 possible (4 rows x <=4 classes)
    __shared__ int lcnt;
    __shared__ int gbase;
    if (threadIdx.x == 0) lcnt = 0;
    __syncthreads();

    const float* lg = logits + (size_t)r * C;
    float v0 = lg[lane];                                  // classes 0..63
    float v1 = (lane < C - 64) ? lg[64 + lane] : -3.4e38f; // classes 64..90
    float m = fmaxf(v0, v1);
    #pragma unroll
    for (int off = 32; off; off >>= 1) m = fmaxf(m, __shfl_xor(m, off, 64));
    float e0 = expf(v0 - m);
    float e1 = (lane < C - 64) ? expf(v1 - m) : 0.0f;
    float s = e0 + e1;
    #pragma unroll
    for (int off = 32; off; off >>= 1) s += __shfl_xor(s, off, 64);

    float p0 = props[r * 4 + 0], p1 = props[r * 4 + 1];
    float p2 = props[r * 4 + 2], p3 = props[r * 4 + 3];
    float wdt = p2 - p0, hgt = p3 - p1;
    float cx = p0 + 0.5f * wdt, cy = p1 + 0.5f * hgt;
    float H = (float)img_hw[b * 2 + 0];
    float W = (float)img_hw[b * 2 + 1];

    #pragma unroll
    for (int t2 = 0; t2 < 2; ++t2) {
        int c = lane + t2 * 64;
        float e = t2 ? e1 : e0;
        if (c >= 1 && c < C) {
            float sc = e / s;
            if (sc > SCORE_THRESH) {
                const float* rg = reg + (size_t)r * (C * 4) + (size_t)c * 4;
                float x1, y1, x2, y2;
                decode_clip(rg, wdt, hgt, cx, cy, W, H, x1, y1, x2, y2);
                if ((x2 - x1) >= MIN_SIZE && (y2 - y1) >= MIN_SIZE) {
                    unsigned int idx = (unsigned int)(n * NC + (c - 1));
                    unsigned long long key =
                        ((unsigned long long)__float_as_uint(sc) << 32) |
                        (unsigned long long)(0xFFFFFFFFu - idx);
                    int p = atomicAdd(&lcnt, 1);          // LDS atomic: cheap
                    cand[p] = key;
                }
            }
        }
    }
    __syncthreads();
    if (threadIdx.x == 0 && lcnt > 0)
        gbase = atomicAdd(&counters[b * CSTRIDE], lcnt);  // one global atomic/block
    __syncthreads();
    if (threadIdx.x < lcnt)
        keys[(size_t)b * PAD + gbase + threadIdx.x] = cand[threadIdx.x];
}

// ---- kernel 2: RANK-AND-SCATTER "sort". Keys are unique u64s, so sorted
// position == #{keys > mine}. 32 blocks/image; block stages all 4096 keys in
// LDS, 2 threads/row scan 2048 entries each (wave-uniform index -> broadcast
// reads, conflict-free, no barriers in the scan). Winning rows (rank < 2048)
// decode their box and scatter straight to bx*/propn[rank]. Bit-identical
// ordering to a full sort; no sorted-key array needed downstream.
__global__ __launch_bounds__(256) void k_rank(const int* __restrict__ counters,
                                              int* __restrict__ Kvals,
                                              const unsigned long long* __restrict__ keys,
                                              const float* __restrict__ reg,
                                              const float* __restrict__ props,
                                              const int* __restrict__ img_hw,
                                              float* __restrict__ bx1, float* __restrict__ by1,
                                              float* __restrict__ bx2, float* __restrict__ by2,
                                              int* __restrict__ propn) {
    __shared__ unsigned long long sk[PAD];   // 32 KB
    __shared__ int pc[256];
    int b = blockIdx.y;
    int V = counters[b * CSTRIDE];
    if (V > PAD) V = PAD;
    const unsigned long long* kb = keys + (size_t)b * PAD;
    for (int t = threadIdx.x; t < PAD; t += 256)
        sk[t] = (t < V) ? kb[t] : 0ULL;      // zero-pad: 0 never outranks a valid key
    __syncthreads();

    int rloc = threadIdx.x & 127;            // row within block
    int half = threadIdx.x >> 7;             // scan half (wave-uniform)
    int row  = blockIdx.x * 128 + rloc;
    unsigned long long my = sk[row];
    int base = half * 2048;
    int cnt = 0;
    #pragma unroll 8
    for (int it = 0; it < 2048; ++it)
        cnt += (sk[base + it] > my) ? 1 : 0;
    pc[threadIdx.x] = cnt;
    __syncthreads();

    if (half == 0 && row < V) {
        int rank = pc[threadIdx.x] + pc[threadIdx.x + 128];
        if (rank < KMAX) {
            unsigned int idx = 0xFFFFFFFFu - (unsigned int)(my & 0xFFFFFFFFull);
            int n = (int)(idx / NC);
            int c = (int)(idx % NC) + 1;
            int r = b * N + n;
            float p0 = props[r * 4 + 0], p1 = props[r * 4 + 1];
            float p2 = props[r * 4 + 2], p3 = props[r * 4 + 3];
            float wdt = p2 - p0, hgt = p3 - p1;
            float cx = p0 + 0.5f * wdt, cy = p1 + 0.5f * hgt;
            float H = (float)img_hw[b * 2 + 0];
            float W = (float)img_hw[b * 2 + 1];
            const float* rg = reg + (size_t)r * (C * 4) + (size_t)c * 4;
            float x1, y1, x2, y2;
            decode_clip(rg, wdt, hgt, cx, cy, W, H, x1, y1, x2, y2);
            size_t o = (size_t)b * KMAX + rank;
            bx1[o] = x1; by1[o] = y1; bx2[o] = x2; by2[o] = y2;
            propn[o] = n;
        }
    }
    if (blockIdx.x == 0 && threadIdx.x == 0)
        Kvals[b] = (V < KMAX) ? V : KMAX;
}

// ---- kernel 3: parallel suppression-mask matrix (unchanged). Slots >= K in
// bx*/propn may be stale; all uses are guarded by j<K / i<K. ----
__global__ __launch_bounds__(256) void k_mask(const int* __restrict__ Kvals,
                                              const float* __restrict__ bx1, const float* __restrict__ by1,
                                              const float* __restrict__ bx2, const float* __restrict__ by2,
                                              unsigned long long* __restrict__ mask) {
    int b = blockIdx.y;
    int K = Kvals[b];
    int base_word = blockIdx.x * 256;
    int row0 = base_word >> 5;
    if (row0 >= K) return;

    __shared__ float sx1[KMAX], sy1[KMAX], sx2[KMAX], sy2[KMAX];
    const float* px1 = bx1 + (size_t)b * KMAX;
    const float* py1 = by1 + (size_t)b * KMAX;
    const float* px2 = bx2 + (size_t)b * KMAX;
    const float* py2 = by2 + (size_t)b * KMAX;
    for (int t = threadIdx.x; t < KMAX; t += 256) {
        sx1[t] = px1[t]; sy1[t] = py1[t]; sx2[t] = px2[t]; sy2[t] = py2[t];
    }
    __syncthreads();

    int word = base_word + threadIdx.x;
    int i = word >> 5, w = word & 31;
    unsigned long long acc = 0ULL;
    if (i < K) {
        float ax1 = sx1[i], ay1 = sy1[i], ax2 = sx2[i], ay2 = sy2[i];
        float aarea = (ax2 - ax1) * (ay2 - ay1);
        for (int bb = 0; bb < 64; ++bb) {
            int off = (bb + w) & 63;          // bank-conflict skew
            int j = (w << 6) + off;
            float q1 = sx1[j], q2 = sy1[j], q3 = sx2[j], q4 = sy2[j];
            float barea = (q3 - q1) * (q4 - q2);
            float ix1 = fmaxf(ax1, q1), iy1 = fmaxf(ay1, q2);
            float ix2 = fminf(ax2, q3), iy2 = fminf(ay2, q4);
            float iw = fmaxf(ix2 - ix1, 0.0f);
            float ih = fmaxf(iy2 - iy1, 0.0f);
            float inter = iw * ih;
            float uni = aarea + barea - inter;
            float iou = (uni > 0.0f) ? (inter / uni) : 0.0f;
            if (j > i && j < K && iou > NMS_THRESH) acc |= (1ULL << off);
        }
        mask[((size_t)b * KMAX + i) * 32 + w] = acc;
    }
}

// ---- kernel 4: bit-parallel sequential scan (unchanged) ----
#define CH 16
__global__ __launch_bounds__(64) void k_scan(const int* __restrict__ Kvals,
                                             const unsigned long long* __restrict__ mask,
                                             const int* __restrict__ propn,
                                             int* __restrict__ sel) {
    int b = blockIdx.x, lane = threadIdx.x;
    int K = Kvals[b];
    const unsigned long long* mb = mask + (size_t)b * KMAX * 32;
    const int* pb = propn + (size_t)b * KMAX;
    unsigned long long removed = 0ULL;
    unsigned long long cur[CH], nxt[CH];
    int pcur = 0, pnxt = 0;
    int cnt = 0;
    bool done = (K <= 0);

    if (!done) {
        #pragma unroll
        for (int q = 0; q < CH; ++q)
            cur[q] = (lane < 32) ? mb[(size_t)q * 32 + lane] : 0ULL;
        pcur = (lane < CH) ? pb[lane] : 0;
    }

    for (int base = 0; base < K; base += CH) {
        if (done) break;
        int nb = base + CH;
        #pragma unroll
        for (int q = 0; q < CH; ++q) {
            int row = nb + q; if (row > KMAX - 1) row = KMAX - 1;
            nxt[q] = (lane < 32) ? mb[(size_t)row * 32 + lane] : 0ULL;
        }
        {
            int row = nb + lane; if (row > KMAX - 1) row = KMAX - 1;
            pnxt = (lane < CH) ? pb[row] : 0;
        }
        #pragma unroll
        for (int q = 0; q < CH; ++q) {
            int i = base + q;
            if (!done && i < K) {
                int owner = i >> 6;
                unsigned long long wword = __shfl(removed, owner, 64); // uniform
                if (!((wword >> (i & 63)) & 1ULL)) {
                    int pv = __shfl(pcur, q, 64);
                    removed |= cur[q];
                    if (lane == 0) sel[b * DETS + cnt] = pv;
                    ++cnt;
                    if (cnt == DETS) done = true;
                }
            }
        }
        #pragma unroll
        for (int q = 0; q < CH; ++q) cur[q] = nxt[q];
        pcur = pnxt;
    }
    if (lane == 0)
        for (int q = cnt; q < DETS; ++q) sel[b * DETS + q] = -1;
}

// ---- kernel 5: gather feature rows (or zeros) into output ----
__global__ __launch_bounds__(256) void k_gather(const int* __restrict__ sel,
                                                const float* __restrict__ feats,
                                                float* __restrict__ out) {
    int slot = blockIdx.x;            // b*DETS + s
    int b = slot / DETS;
    int row = sel[slot];
    float4* o = (float4*)(out + (size_t)slot * D);
    if (row >= 0) {
        const float4* f = (const float4*)(feats + ((size_t)b * N + row) * D);
        o[threadIdx.x] = f[threadIdx.x];
    } else {
        o[threadIdx.x] = make_float4(0.f, 0.f, 0.f, 0.f);
    }
}

extern "C" void kernel_launch(void* const* d_in, const int* in_sizes, int n_in,
                              void* d_out, int out_size, void* d_ws, size_t ws_size,
                              hipStream_t stream) {
    const float* logits = (const float*)d_in[0];   // [B,N,C]
    const float* reg    = (const float*)d_in[1];   // [B,N,C*4]
    const float* props  = (const float*)d_in[2];   // [B,N,4]
    const float* feats  = (const float*)d_in[3];   // [B,N,D]
    const int*   img    = (const int*)d_in[4];     // [B,2]
    float* out = (float*)d_out;                    // [B,DETS,D]

    char* ws = (char*)d_ws;
    int* counters = (int*)(ws + 0);                        // 8 ints padded to 256 B each
    int* Kvals    = (int*)(ws + 2048);                     // 8 ints
    int* sel      = (int*)(ws + 2304);                     // 8*36 ints
    unsigned long long* keys = (unsigned long long*)(ws + 4096);      // 8*4096 u64 = 256KB
    float* bx1 = (float*)(ws + 270336);                    // each 8*2048*4 = 64KB
    float* by1 = (float*)(ws + 335872);
    float* bx2 = (float*)(ws + 401408);
    float* by2 = (float*)(ws + 466944);
    int*   propn = (int*)(ws + 532480);                    // 64KB
    unsigned long long* mask = (unsigned long long*)(ws + 598016);    // 8*2048*32 u64 = 4MB

    hipMemsetAsync(counters, 0, 2048, stream);
    k_score<<<dim3(B * 250), dim3(256), 0, stream>>>(
        logits, reg, props, img, counters, keys);
    k_rank<<<dim3(32, B), dim3(256), 0, stream>>>(counters, Kvals, keys,
        reg, props, img, bx1, by1, bx2, by2, propn);
    k_mask<<<dim3(256, B), dim3(256), 0, stream>>>(Kvals, bx1, by1, bx2, by2, mask);
    k_scan<<<dim3(B), dim3(64), 0, stream>>>(Kvals, mask, propn, sel);
    k_gather<<<dim3(B * DETS), dim3(256), 0, stream>>>(sel, feats, out);
}

// Round 5
// 122.015 us; speedup vs baseline: 7.8918x; 1.3399x over previous
//
#include <hip/hip_runtime.h>
#include <stdint.h>

#define B 8
#define N 1000
#define C 91
#define NC 90            // classes minus background
#define D 1024
#define KMAX 2048        // NMS_TOPK
#define PAD 4096         // key slots/image: 4*N=4000 used (<=4 classes/row can have softmax>0.2), rest zero
#define DETS 36
#define SCORE_THRESH 0.2f
#define NMS_THRESH 0.5f
#define MIN_SIZE 0.01f
#define XFORM_CLIP 4.135166556742356f   // log(1000/16)

// ---- shared decode so all kernels produce bit-identical boxes ----
__device__ __forceinline__ void decode_clip(const float* __restrict__ rg,
                                            float wdt, float hgt, float cx, float cy,
                                            float W, float H,
                                            float& x1, float& y1, float& x2, float& y2) {
    float dx = rg[0] / 10.0f;
    float dy = rg[1] / 10.0f;
    float dw = fminf(rg[2] / 5.0f, XFORM_CLIP);
    float dh = fminf(rg[3] / 5.0f, XFORM_CLIP);
    float pcx = dx * wdt + cx;
    float pcy = dy * hgt + cy;
    float pw  = expf(dw) * wdt;
    float ph  = expf(dh) * hgt;
    x1 = fminf(fmaxf(pcx - 0.5f * pw, 0.0f), W);
    y1 = fminf(fmaxf(pcy - 0.5f * ph, 0.0f), H);
    x2 = fminf(fmaxf(pcx + 0.5f * pw, 0.0f), W);
    y2 = fminf(fmaxf(pcy + 0.5f * ph, 0.0f), H);
}

// ---- kernel 1: wave-per-row class-parallel softmax + decode + filter.
// Candidates go to FIXED slots keys[n*4 + p] via ballot compaction (p<4
// guaranteed: 5 softmax values > 0.2 would sum > 1). Empty slots = 0, which
// never outranks a valid key (valid keys have score bits >= 0x3E4CCCCD).
// No atomics, no counter memset.
__global__ __launch_bounds__(256) void k_score(const float* __restrict__ logits,
                        const float* __restrict__ reg,
                        const float* __restrict__ props,
                        const int* __restrict__ img_hw,
                        unsigned long long* __restrict__ keys) {
    int b = blockIdx.x / 250;            // 250 blocks per image, 4 rows per block
    int local = blockIdx.x % 250;
    int wib = threadIdx.x >> 6, lane = threadIdx.x & 63;
    int n = local * 4 + wib;
    int r = b * N + n;

    __shared__ unsigned long long slot[4][4];
    if (threadIdx.x < 16) slot[threadIdx.x >> 2][threadIdx.x & 3] = 0ULL;
    __syncthreads();

    const float* lg = logits + (size_t)r * C;
    float v0 = lg[lane];                                   // classes 0..63
    float v1 = (lane < C - 64) ? lg[64 + lane] : -3.4e38f; // classes 64..90
    float m = fmaxf(v0, v1);
    #pragma unroll
    for (int off = 32; off; off >>= 1) m = fmaxf(m, __shfl_xor(m, off, 64));
    float e0 = expf(v0 - m);
    float e1 = (lane < C - 64) ? expf(v1 - m) : 0.0f;
    float s = e0 + e1;
    #pragma unroll
    for (int off = 32; off; off >>= 1) s += __shfl_xor(s, off, 64);

    float p0 = props[r * 4 + 0], p1 = props[r * 4 + 1];
    float p2 = props[r * 4 + 2], p3 = props[r * 4 + 3];
    float wdt = p2 - p0, hgt = p3 - p1;
    float cx = p0 + 0.5f * wdt, cy = p1 + 0.5f * hgt;
    float H = (float)img_hw[b * 2 + 0];
    float W = (float)img_hw[b * 2 + 1];

    unsigned long long keyv[2] = {0ULL, 0ULL};
    #pragma unroll
    for (int t2 = 0; t2 < 2; ++t2) {
        int c = lane + t2 * 64;
        float e = t2 ? e1 : e0;
        if (c >= 1 && c < C) {
            float sc = e / s;
            if (sc > SCORE_THRESH) {
                const float* rg = reg + (size_t)r * (C * 4) + (size_t)c * 4;
                float x1, y1, x2, y2;
                decode_clip(rg, wdt, hgt, cx, cy, W, H, x1, y1, x2, y2);
                if ((x2 - x1) >= MIN_SIZE && (y2 - y1) >= MIN_SIZE) {
                    unsigned int idx = (unsigned int)(n * NC + (c - 1));
                    keyv[t2] = ((unsigned long long)__float_as_uint(sc) << 32) |
                               (unsigned long long)(0xFFFFFFFFu - idx);
                }
            }
        }
    }
    unsigned long long m0 = __ballot(keyv[0] != 0ULL);
    unsigned long long m1 = __ballot(keyv[1] != 0ULL);
    unsigned long long lower = (1ULL << lane) - 1ULL;
    if (keyv[0]) slot[wib][__popcll(m0 & lower)] = keyv[0];
    if (keyv[1]) slot[wib][__popcll(m0) + __popcll(m1 & lower)] = keyv[1];
    __syncthreads();
    if (threadIdx.x < 16) {
        int ww = threadIdx.x >> 2, p = threadIdx.x & 3;
        keys[(size_t)b * PAD + (size_t)(local * 4 + ww) * 4 + p] = slot[ww][p];
    }
}

// ---- kernel 2: rank-and-scatter. sorted position == #{keys > mine} (keys
// unique; zeros rank last). 64 blocks/image (2 blocks/CU -> 8 waves/CU for
// latency hiding); 4 threads/row, each scans 1024 of 4096 keys via wave-
// uniform LDS broadcast reads. Winning rows decode + scatter to rank slot.
// Row 4*N is always zero-keyed: its rank == V_valid -> writes Kvals for free.
__global__ __launch_bounds__(256) void k_rank(int* __restrict__ Kvals,
                                              const unsigned long long* __restrict__ keys,
                                              const float* __restrict__ reg,
                                              const float* __restrict__ props,
                                              const int* __restrict__ img_hw,
                                              float* __restrict__ bx1, float* __restrict__ by1,
                                              float* __restrict__ bx2, float* __restrict__ by2,
                                              int* __restrict__ propn) {
    __shared__ unsigned long long sk[PAD];   // 32 KB
    __shared__ int pc[256];
    int b = blockIdx.y;
    const unsigned long long* kb = keys + (size_t)b * PAD;
    for (int t = threadIdx.x; t < PAD; t += 256)
        sk[t] = (t < 4 * N) ? kb[t] : 0ULL;
    __syncthreads();

    int rloc = threadIdx.x & 63;
    int quarter = threadIdx.x >> 6;          // wave-uniform
    int row = blockIdx.x * 64 + rloc;
    unsigned long long my = sk[row];
    int base = quarter * 1024;
    int cnt = 0;
    #pragma unroll 8
    for (int it = 0; it < 1024; ++it)
        cnt += (sk[base + it] > my) ? 1 : 0;
    pc[threadIdx.x] = cnt;
    __syncthreads();

    if (quarter == 0) {
        int rank = pc[rloc] + pc[rloc + 64] + pc[rloc + 128] + pc[rloc + 192];
        if (row == 4 * N) Kvals[b] = (rank < KMAX) ? rank : KMAX;  // rank of a zero key == V_valid
        if (my != 0ULL && rank < KMAX) {
            unsigned int idx = 0xFFFFFFFFu - (unsigned int)(my & 0xFFFFFFFFull);
            int n = (int)(idx / NC);
            int c = (int)(idx % NC) + 1;
            int r = b * N + n;
            float p0 = props[r * 4 + 0], p1 = props[r * 4 + 1];
            float p2 = props[r * 4 + 2], p3 = props[r * 4 + 3];
            float wdt = p2 - p0, hgt = p3 - p1;
            float cx = p0 + 0.5f * wdt, cy = p1 + 0.5f * hgt;
            float H = (float)img_hw[b * 2 + 0];
            float W = (float)img_hw[b * 2 + 1];
            const float* rg = reg + (size_t)r * (C * 4) + (size_t)c * 4;
            float x1, y1, x2, y2;
            decode_clip(rg, wdt, hgt, cx, cy, W, H, x1, y1, x2, y2);
            size_t o = (size_t)b * KMAX + rank;
            bx1[o] = x1; by1[o] = y1; bx2[o] = x2; by2[o] = y2;
            propn[o] = n;
        }
    }
}

// ---- kernel 3: fused greedy NMS, one wave per image. Suppression only flows
// from KEPT candidates (<=36), so no 2048x2048 mask: per 64-candidate chunk,
// each lane checks its box vs the kept list, then in-chunk resolution pops
// the lowest live rank via __ffsll + broadcast (serial steps == #kept, and
// self-IoU=1 clears the popped bit automatically). Early exit at 36 kept ==
// reference's first-36-of-keep-set (kept enumerated in increasing rank).
__global__ __launch_bounds__(64) void k_nms(const int* __restrict__ Kvals,
                                            const float* __restrict__ bx1, const float* __restrict__ by1,
                                            const float* __restrict__ bx2, const float* __restrict__ by2,
                                            const int* __restrict__ propn,
                                            int* __restrict__ sel) {
    __shared__ float kx1[DETS], ky1[DETS], kx2[DETS], ky2[DETS];
    __shared__ int kpn[DETS];
    int b = blockIdx.x, lane = threadIdx.x;
    int K = Kvals[b];
    size_t ofs = (size_t)b * KMAX;
    int kept = 0;

    for (int cs = 0; cs < K && kept < DETS; cs += 64) {
        int j = cs + lane;
        bool inr = (j < K);
        int jj = inr ? j : 0;
        float x1 = bx1[ofs + jj], y1 = by1[ofs + jj];
        float x2 = bx2[ofs + jj], y2 = by2[ofs + jj];
        int pn = propn[ofs + jj];
        float area = (x2 - x1) * (y2 - y1);

        bool supp = !inr;
        for (int k = 0; k < kept; ++k) {             // vs kept from earlier chunks
            float c1 = kx1[k], c2 = ky1[k], c3 = kx2[k], c4 = ky2[k];
            float carea = (c3 - c1) * (c4 - c2);
            float ix1 = fmaxf(c1, x1), iy1 = fmaxf(c2, y1);
            float ix2 = fminf(c3, x2), iy2 = fminf(c4, y2);
            float iw = fmaxf(ix2 - ix1, 0.0f), ih = fmaxf(iy2 - iy1, 0.0f);
            float inter = iw * ih;
            float uni = carea + area - inter;
            float iou = (uni > 0.0f) ? (inter / uni) : 0.0f;
            supp = supp || (iou > NMS_THRESH);
        }
        unsigned long long live = __ballot(!supp);
        while (live != 0ULL && kept < DETS) {
            int i = __ffsll((unsigned long long)live) - 1;
            float c1 = __shfl(x1, i, 64), c2 = __shfl(y1, i, 64);
            float c3 = __shfl(x2, i, 64), c4 = __shfl(y2, i, 64);
            int   cp = __shfl(pn, i, 64);
            if (lane == 0) { kx1[kept] = c1; ky1[kept] = c2; kx2[kept] = c3; ky2[kept] = c4; kpn[kept] = cp; }
            kept++;
            float carea = (c3 - c1) * (c4 - c2);
            float ix1 = fmaxf(c1, x1), iy1 = fmaxf(c2, y1);
            float ix2 = fminf(c3, x2), iy2 = fminf(c4, y2);
            float iw = fmaxf(ix2 - ix1, 0.0f), ih = fmaxf(iy2 - iy1, 0.0f);
            float inter = iw * ih;
            float uni = carea + area - inter;
            float iou = (uni > 0.0f) ? (inter / uni) : 0.0f;
            live &= ~__ballot(iou > NMS_THRESH);     // clears bit i too (self IoU=1)
        }
    }
    __syncthreads();                                  // single wave: cheap, orders LDS
    if (lane < DETS) sel[b * DETS + lane] = (lane < kept) ? kpn[lane] : -1;
}

// ---- kernel 4: gather feature rows (or zeros) into output ----
__global__ __launch_bounds__(256) void k_gather(const int* __restrict__ sel,
                                                const float* __restrict__ feats,
                                                float* __restrict__ out) {
    int slot = blockIdx.x;            // b*DETS + s
    int b = slot / DETS;
    int row = sel[slot];
    float4* o = (float4*)(out + (size_t)slot * D);
    if (row >= 0) {
        const float4* f = (const float4*)(feats + ((size_t)b * N + row) * D);
        o[threadIdx.x] = f[threadIdx.x];
    } else {
        o[threadIdx.x] = make_float4(0.f, 0.f, 0.f, 0.f);
    }
}

extern "C" void kernel_launch(void* const* d_in, const int* in_sizes, int n_in,
                              void* d_out, int out_size, void* d_ws, size_t ws_size,
                              hipStream_t stream) {
    const float* logits = (const float*)d_in[0];   // [B,N,C]
    const float* reg    = (const float*)d_in[1];   // [B,N,C*4]
    const float* props  = (const float*)d_in[2];   // [B,N,4]
    const float* feats  = (const float*)d_in[3];   // [B,N,D]
    const int*   img    = (const int*)d_in[4];     // [B,2]
    float* out = (float*)d_out;                    // [B,DETS,D]

    char* ws = (char*)d_ws;
    int* Kvals    = (int*)(ws + 0);                        // 8 ints (written unconditionally by k_rank)
    int* sel      = (int*)(ws + 256);                      // 8*36 ints (fully written by k_nms)
    unsigned long long* keys = (unsigned long long*)(ws + 4096);      // 8*4096 u64 = 256KB (fully written by k_score)
    float* bx1 = (float*)(ws + 270336);                    // each 8*2048*4 = 64KB (ranks >= K guarded)
    float* by1 = (float*)(ws + 335872);
    float* bx2 = (float*)(ws + 401408);
    float* by2 = (float*)(ws + 466944);
    int*   propn = (int*)(ws + 532480);                    // 64KB

    k_score<<<dim3(B * 250), dim3(256), 0, stream>>>(logits, reg, props, img, keys);
    k_rank<<<dim3(64, B), dim3(256), 0, stream>>>(Kvals, keys,
        reg, props, img, bx1, by1, bx2, by2, propn);
    k_nms<<<dim3(B), dim3(64), 0, stream>>>(Kvals, bx1, by1, bx2, by2, propn, sel);
    k_gather<<<dim3(B * DETS), dim3(256), 0, stream>>>(sel, feats, out);
}